// Round 1
// baseline (398.325 us; speedup 1.0000x reference)
//
#include <hip/hip_runtime.h>

typedef unsigned short u16;
typedef __attribute__((ext_vector_type(8))) __bf16 bf16x8;
typedef __attribute__((ext_vector_type(4))) float f32x4;

// Problem dims
#define BB 32
#define LL 512
#define CC 512
#define HH 8
#define DH 64
#define MROWS (BB * LL)        // 16384
#define NQKV  (3 * CC)         // 1536

// workspace layout (bytes)
#define XB_BYTES ((size_t)MROWS * CC * 2)        // 16,777,216  (x bf16; later reused as vT)
#define WC_BYTES ((size_t)NQKV * CC * 2)         //  1,572,864  (wq|wk|wv bf16)
#define QKV_OFF  (XB_BYTES + WC_BYTES)           // qkv bf16: MROWS x 1536

__device__ inline u16 f2b(float f) {
  union { float f; unsigned u; } a; a.f = f;
  unsigned u = a.u;
  return (u16)((u + 0x7FFFu + ((u >> 16) & 1u)) >> 16);   // RNE, inputs are finite
}

// ---------------- conversion kernels ----------------
__global__ __launch_bounds__(256) void cvt_x(const float* __restrict__ x, u16* __restrict__ xb) {
  int i = blockIdx.x * 256 + threadIdx.x;       // one float4 per thread
  float4 v = ((const float4*)x)[i];
  ushort4 o;
  o.x = f2b(v.x); o.y = f2b(v.y); o.z = f2b(v.z); o.w = f2b(v.w);
  ((ushort4*)xb)[i] = o;
}

__global__ __launch_bounds__(256) void cvt_w(const float* __restrict__ wq, const float* __restrict__ wk,
                                             const float* __restrict__ wv, u16* __restrict__ wcat) {
  int i = blockIdx.x * 256 + threadIdx.x;       // one float4 per thread
  int e = i * 4;
  int n = e >> 9;                                // output row 0..1535
  int k = e & 511;
  const float* src = (n < 512) ? (wq + (size_t)n * 512)
                   : (n < 1024) ? (wk + (size_t)(n - 512) * 512)
                                : (wv + (size_t)(n - 1024) * 512);
  float4 v = *(const float4*)(src + k);
  ushort4 o;
  o.x = f2b(v.x); o.y = f2b(v.y); o.z = f2b(v.z); o.w = f2b(v.w);
  *(ushort4*)(wcat + (size_t)n * 512 + k) = o;
}

// ---------------- async global->LDS ----------------
typedef __attribute__((address_space(1))) void* as1_void_p;
typedef __attribute__((address_space(3))) void* as3_void_p;

__device__ inline void async16(const u16* g, u16* l) {
#if __has_builtin(__builtin_amdgcn_global_load_lds)
  __builtin_amdgcn_global_load_lds((as1_void_p)g, (as3_void_p)l, 16, 0, 0);
#else
  *(uint4*)l = *(const uint4*)g;
#endif
}

// ---------------- QKV projection GEMM ----------------
// A: xb (MROWS x 512 bf16, row-major), Bw: wcat (1536 x 512 bf16, row-major; y = x @ W^T)
// C: qkv (MROWS x 1536 bf16)
__global__ __launch_bounds__(256) void gemm_qkv(const u16* __restrict__ A, const u16* __restrict__ Bw,
                                                u16* __restrict__ Cm) {
  __shared__ u16 a_lds[128 * 32];
  __shared__ u16 b_lds[128 * 32];
  const int n0 = blockIdx.x * 128, m0 = blockIdx.y * 128;
  const int t = threadIdx.x, l = t & 63;
  const int wrow = ((t >> 7) & 1) * 64, wcol = ((t >> 6) & 1) * 64;
  const int lr = l & 15, lq = l >> 4;

  f32x4 acc[4][4] = {};

  for (int k0 = 0; k0 < 512; k0 += 32) {
    {
      int c0 = t, c1 = t + 256;
      async16(A  + (size_t)(m0 + (c0 >> 2)) * 512 + k0 + (c0 & 3) * 8, &a_lds[c0 * 8]);
      async16(A  + (size_t)(m0 + (c1 >> 2)) * 512 + k0 + (c1 & 3) * 8, &a_lds[c1 * 8]);
      async16(Bw + (size_t)(n0 + (c0 >> 2)) * 512 + k0 + (c0 & 3) * 8, &b_lds[c0 * 8]);
      async16(Bw + (size_t)(n0 + (c1 >> 2)) * 512 + k0 + (c1 & 3) * 8, &b_lds[c1 * 8]);
    }
    __syncthreads();
    bf16x8 af[4], bfr[4];
#pragma unroll
    for (int r = 0; r < 4; ++r) af[r]  = *(const bf16x8*)&a_lds[(wrow + r * 16 + lr) * 32 + lq * 8];
#pragma unroll
    for (int c = 0; c < 4; ++c) bfr[c] = *(const bf16x8*)&b_lds[(wcol + c * 16 + lr) * 32 + lq * 8];
#pragma unroll
    for (int r = 0; r < 4; ++r)
#pragma unroll
      for (int c = 0; c < 4; ++c)
        acc[r][c] = __builtin_amdgcn_mfma_f32_16x16x32_bf16(af[r], bfr[c], acc[r][c], 0, 0, 0);
    __syncthreads();
  }
  // epilogue: C/D layout col=lane&15, row=(lane>>4)*4+reg
#pragma unroll
  for (int r = 0; r < 4; ++r) {
#pragma unroll
    for (int i = 0; i < 4; ++i) {
      int m = m0 + wrow + r * 16 + lq * 4 + i;
      u16* crow = Cm + (size_t)m * NQKV + n0 + wcol;
#pragma unroll
      for (int c = 0; c < 4; ++c)
        crow[c * 16 + lr] = f2b(acc[r][c][i]);
    }
  }
}

// ---------------- V transpose: qkv V-part (b,l,h,d) -> vT[(b*8+h)*64+d][l] ----------------
__global__ __launch_bounds__(256) void transpose_v(const u16* __restrict__ qkv, u16* __restrict__ vT) {
  const int bh = blockIdx.x;                 // 0..255
  const int b = bh >> 3, h = bh & 7;
  const int lc0 = blockIdx.y * 128;
  __shared__ u16 tile[32 * 72];              // pad row stride 72 (16B aligned)
  const int t = threadIdx.x;
  for (int lc = lc0; lc < lc0 + 128; lc += 32) {
    int lrow = t >> 3, dcol = (t & 7) * 8;
    const u16* src = qkv + (size_t)(b * 512 + lc + lrow) * NQKV + 1024 + h * 64 + dcol;
    *(uint4*)&tile[lrow * 72 + dcol] = *(const uint4*)src;
    __syncthreads();
    int d = t >> 2, lp = (t & 3) * 8;
    union { ushort4 v4[2]; u16 s[8]; } tmp;
#pragma unroll
    for (int j = 0; j < 8; ++j) tmp.s[j] = tile[(lp + j) * 72 + d];
    *(uint4*)&vT[(size_t)(bh * 64 + d) * 512 + lc + lp] = *(uint4*)&tmp;
    __syncthreads();
  }
}

// ---------------- fused attention ----------------
// block: (q-tile of 16) x h x b ; 256 threads = 4 waves
__global__ __launch_bounds__(256) void attn_kernel(const u16* __restrict__ qkv, const u16* __restrict__ vT,
                                                   const float* __restrict__ bias_table,
                                                   float* __restrict__ out) {
  __shared__ float s_lds[16 * 514];          // stride 514: S-writes 2-way (free), PV reads <=4-way
  const int b = blockIdx.z, h = blockIdx.y, q0 = blockIdx.x * 16;
  const int t = threadIdx.x, l = t & 63, w = t >> 6;
  const int lr = l & 15, lq = l >> 4;
  const float scale = 0.044194173824159216f; // 512^-0.5 (full C, per reference)

  // Q A-frags (row-tile of 16 queries, K-dim = DH in 2 chunks of 32)
  bf16x8 aq0, aq1;
  {
    const u16* qrow = qkv + (size_t)(b * 512 + q0 + lr) * NQKV + h * 64;
    aq0 = *(const bf16x8*)(qrow + lq * 8);
    aq1 = *(const bf16x8*)(qrow + 32 + lq * 8);
  }
  // S = Q K^T * scale ; wave w owns key-cols [w*128, w*128+128)
#pragma unroll
  for (int ct = 0; ct < 8; ++ct) {
    const int kcol = w * 128 + ct * 16;
    const u16* krow = qkv + (size_t)(b * 512 + kcol + lr) * NQKV + 512 + h * 64;
    bf16x8 bk0 = *(const bf16x8*)(krow + lq * 8);
    bf16x8 bk1 = *(const bf16x8*)(krow + 32 + lq * 8);
    f32x4 acc = {0.f, 0.f, 0.f, 0.f};
    acc = __builtin_amdgcn_mfma_f32_16x16x32_bf16(aq0, bk0, acc, 0, 0, 0);
    acc = __builtin_amdgcn_mfma_f32_16x16x32_bf16(aq1, bk1, acc, 0, 0, 0);
#pragma unroll
    for (int i = 0; i < 4; ++i)
      s_lds[(lq * 4 + i) * 514 + kcol + lr] = acc[i] * scale;
  }
  __syncthreads();

  // softmax + post-softmax bias; 16 threads per row, 32 cols each (stride 16)
  {
    const int r = t >> 4, sub = t & 15;
    float v[32];
    float m = -1e30f;
#pragma unroll
    for (int j = 0; j < 32; ++j) { v[j] = s_lds[r * 514 + sub + j * 16]; m = fmaxf(m, v[j]); }
#pragma unroll
    for (int d = 1; d < 16; d <<= 1) m = fmaxf(m, __shfl_xor(m, d, 64));
    float s = 0.f;
#pragma unroll
    for (int j = 0; j < 32; ++j) { v[j] = expf(v[j] - m); s += v[j]; }
#pragma unroll
    for (int d = 1; d < 16; d <<= 1) s += __shfl_xor(s, d, 64);
    const float rinv = 1.0f / s;
    const int qg = q0 + r;
#pragma unroll
    for (int j = 0; j < 32; ++j) {
      int col = sub + j * 16;
      float bias = bias_table[(size_t)(col - qg + 511) * HH + h];
      s_lds[r * 514 + col] = v[j] * rinv + bias;
    }
  }
  __syncthreads();

  // out = P @ V ; wave w owns d-tile [w*16, w*16+16)
  f32x4 acc = {0.f, 0.f, 0.f, 0.f};
  const u16* vrow = vT + (size_t)((b * 8 + h) * 64 + w * 16 + lr) * 512;
  for (int kt = 0; kt < 16; ++kt) {
    union { bf16x8 v; u16 s[8]; } ap;
#pragma unroll
    for (int j = 0; j < 8; ++j) ap.s[j] = f2b(s_lds[lr * 514 + kt * 32 + lq * 8 + j]);
    bf16x8 bv = *(const bf16x8*)(vrow + kt * 32 + lq * 8);
    acc = __builtin_amdgcn_mfma_f32_16x16x32_bf16(ap.v, bv, acc, 0, 0, 0);
  }
#pragma unroll
  for (int i = 0; i < 4; ++i) {
    int qg = q0 + lq * 4 + i;
    out[(size_t)(b * 512 + qg) * 512 + h * 64 + w * 16 + lr] = acc[i];
  }
}

// ---------------- LayerNorm (in-place on d_out) ----------------
__global__ __launch_bounds__(256) void ln_kernel(float* __restrict__ out,
                                                 const float* __restrict__ gamma,
                                                 const float* __restrict__ beta) {
  const int row = blockIdx.x;
  float* p = out + (size_t)row * 512;
  const int t = threadIdx.x;
  float a = p[t], b2 = p[t + 256];
  float s = a + b2, s2 = a * a + b2 * b2;
#pragma unroll
  for (int d = 1; d < 64; d <<= 1) { s += __shfl_xor(s, d, 64); s2 += __shfl_xor(s2, d, 64); }
  __shared__ float ps[4], ps2[4];
  if ((t & 63) == 0) { ps[t >> 6] = s; ps2[t >> 6] = s2; }
  __syncthreads();
  s = ps[0] + ps[1] + ps[2] + ps[3];
  s2 = ps2[0] + ps2[1] + ps2[2] + ps2[3];
  float mu = s * (1.0f / 512.0f);
  float var = s2 * (1.0f / 512.0f) - mu * mu;
  float rs = rsqrtf(var + 1e-5f);
  p[t]       = gamma[t]       * (a  - mu) * rs + beta[t];
  p[t + 256] = gamma[t + 256] * (b2 - mu) * rs + beta[t + 256];
}

extern "C" void kernel_launch(void* const* d_in, const int* in_sizes, int n_in,
                              void* d_out, int out_size, void* d_ws, size_t ws_size,
                              hipStream_t stream) {
  const float* x    = (const float*)d_in[0];
  const float* wq   = (const float*)d_in[1];
  const float* wk   = (const float*)d_in[2];
  const float* wv   = (const float*)d_in[3];
  const float* bias = (const float*)d_in[4];
  const float* gamma = (const float*)d_in[5];
  const float* beta  = (const float*)d_in[6];
  float* out = (float*)d_out;

  char* ws = (char*)d_ws;
  u16* xb   = (u16*)ws;                       // x in bf16 (reused as vT afterwards)
  u16* wcat = (u16*)(ws + XB_BYTES);          // concat weights bf16
  u16* qkv  = (u16*)(ws + QKV_OFF);           // MROWS x 1536 bf16
  u16* vT   = xb;                             // reuse: gemm is done with xb before transpose

  cvt_x<<<dim3((MROWS * CC) / 4 / 256), 256, 0, stream>>>(x, xb);
  cvt_w<<<dim3((NQKV * CC) / 4 / 256), 256, 0, stream>>>(wq, wk, wv, wcat);
  gemm_qkv<<<dim3(NQKV / 128, MROWS / 128), 256, 0, stream>>>(xb, wcat, qkv);
  transpose_v<<<dim3(256, 4), 256, 0, stream>>>(qkv, vT);
  attn_kernel<<<dim3(32, 8, 32), 256, 0, stream>>>(qkv, vT, bias, out);
  ln_kernel<<<dim3(MROWS), 256, 0, stream>>>(out, gamma, beta);
}

// Round 2
// 290.638 us; speedup vs baseline: 1.3705x; 1.3705x over previous
//
#include <hip/hip_runtime.h>

typedef unsigned short u16;
typedef __attribute__((ext_vector_type(8))) __bf16 bf16x8;
typedef __attribute__((ext_vector_type(4))) float f32x4;

// Problem dims
#define BB 32
#define LL 512
#define CC 512
#define HH 8
#define DH 64
#define MROWS (BB * LL)        // 16384
#define NQKV  (3 * CC)         // 1536

// workspace layout (bytes)
#define XB_BYTES ((size_t)MROWS * CC * 2)        // 16,777,216  (x bf16; later reused as vT)
#define WC_BYTES ((size_t)NQKV * CC * 2)         //  1,572,864  (wq|wk|wv bf16)
#define QKV_OFF  (XB_BYTES + WC_BYTES)           // qkv bf16: MROWS x 1536

__device__ inline u16 f2b(float f) {
  union { float f; unsigned u; } a; a.f = f;
  unsigned u = a.u;
  return (u16)((u + 0x7FFFu + ((u >> 16) & 1u)) >> 16);   // RNE, inputs are finite
}

// ---------------- conversion kernels ----------------
__global__ __launch_bounds__(256) void cvt_x(const float* __restrict__ x, u16* __restrict__ xb) {
  int i = blockIdx.x * 256 + threadIdx.x;       // one float4 per thread
  float4 v = ((const float4*)x)[i];
  ushort4 o;
  o.x = f2b(v.x); o.y = f2b(v.y); o.z = f2b(v.z); o.w = f2b(v.w);
  ((ushort4*)xb)[i] = o;
}

__global__ __launch_bounds__(256) void cvt_w(const float* __restrict__ wq, const float* __restrict__ wk,
                                             const float* __restrict__ wv, u16* __restrict__ wcat) {
  int i = blockIdx.x * 256 + threadIdx.x;       // one float4 per thread
  int e = i * 4;
  int n = e >> 9;                                // output row 0..1535
  int k = e & 511;
  const float* src = (n < 512) ? (wq + (size_t)n * 512)
                   : (n < 1024) ? (wk + (size_t)(n - 512) * 512)
                                : (wv + (size_t)(n - 1024) * 512);
  float4 v = *(const float4*)(src + k);
  ushort4 o;
  o.x = f2b(v.x); o.y = f2b(v.y); o.z = f2b(v.z); o.w = f2b(v.w);
  *(ushort4*)(wcat + (size_t)n * 512 + k) = o;
}

// ---------------- async global->LDS ----------------
typedef __attribute__((address_space(1))) void* as1_void_p;
typedef __attribute__((address_space(3))) void* as3_void_p;

__device__ inline void async16(const u16* g, u16* l) {
#if __has_builtin(__builtin_amdgcn_global_load_lds)
  __builtin_amdgcn_global_load_lds((as1_void_p)g, (as3_void_p)l, 16, 0, 0);
#else
  *(uint4*)l = *(const uint4*)g;
#endif
}

// ---------------- QKV projection GEMM ----------------
// A: xb (MROWS x 512 bf16, row-major), Bw: wcat (1536 x 512 bf16, row-major; y = x @ W^T)
// C: qkv (MROWS x 1536 bf16)
__global__ __launch_bounds__(256) void gemm_qkv(const u16* __restrict__ A, const u16* __restrict__ Bw,
                                                u16* __restrict__ Cm) {
  __shared__ u16 a_lds[128 * 32];
  __shared__ u16 b_lds[128 * 32];
  const int n0 = blockIdx.x * 128, m0 = blockIdx.y * 128;
  const int t = threadIdx.x, l = t & 63;
  const int wrow = ((t >> 7) & 1) * 64, wcol = ((t >> 6) & 1) * 64;
  const int lr = l & 15, lq = l >> 4;

  f32x4 acc[4][4] = {};

  for (int k0 = 0; k0 < 512; k0 += 32) {
    {
      int c0 = t, c1 = t + 256;
      async16(A  + (size_t)(m0 + (c0 >> 2)) * 512 + k0 + (c0 & 3) * 8, &a_lds[c0 * 8]);
      async16(A  + (size_t)(m0 + (c1 >> 2)) * 512 + k0 + (c1 & 3) * 8, &a_lds[c1 * 8]);
      async16(Bw + (size_t)(n0 + (c0 >> 2)) * 512 + k0 + (c0 & 3) * 8, &b_lds[c0 * 8]);
      async16(Bw + (size_t)(n0 + (c1 >> 2)) * 512 + k0 + (c1 & 3) * 8, &b_lds[c1 * 8]);
    }
    __syncthreads();
    bf16x8 af[4], bfr[4];
#pragma unroll
    for (int r = 0; r < 4; ++r) af[r]  = *(const bf16x8*)&a_lds[(wrow + r * 16 + lr) * 32 + lq * 8];
#pragma unroll
    for (int c = 0; c < 4; ++c) bfr[c] = *(const bf16x8*)&b_lds[(wcol + c * 16 + lr) * 32 + lq * 8];
#pragma unroll
    for (int r = 0; r < 4; ++r)
#pragma unroll
      for (int c = 0; c < 4; ++c)
        acc[r][c] = __builtin_amdgcn_mfma_f32_16x16x32_bf16(af[r], bfr[c], acc[r][c], 0, 0, 0);
    __syncthreads();
  }
  // epilogue: C/D layout col=lane&15, row=(lane>>4)*4+reg
#pragma unroll
  for (int r = 0; r < 4; ++r) {
#pragma unroll
    for (int i = 0; i < 4; ++i) {
      int m = m0 + wrow + r * 16 + lq * 4 + i;
      u16* crow = Cm + (size_t)m * NQKV + n0 + wcol;
#pragma unroll
      for (int c = 0; c < 4; ++c)
        crow[c * 16 + lr] = f2b(acc[r][c][i]);
    }
  }
}

// ---------------- V transpose: qkv V-part (b,l,h,d) -> vT[(b*8+h)*64+d][l] ----------------
__global__ __launch_bounds__(256) void transpose_v(const u16* __restrict__ qkv, u16* __restrict__ vT) {
  const int bh = blockIdx.x;                 // 0..255
  const int b = bh >> 3, h = bh & 7;
  const int lc0 = blockIdx.y * 128;
  __shared__ u16 tile[32 * 72];              // pad row stride 72 (16B aligned)
  const int t = threadIdx.x;
  for (int lc = lc0; lc < lc0 + 128; lc += 32) {
    int lrow = t >> 3, dcol = (t & 7) * 8;
    const u16* src = qkv + (size_t)(b * 512 + lc + lrow) * NQKV + 1024 + h * 64 + dcol;
    *(uint4*)&tile[lrow * 72 + dcol] = *(const uint4*)src;
    __syncthreads();
    int d = t >> 2, lp = (t & 3) * 8;
    union { ushort4 v4[2]; u16 s[8]; } tmp;
#pragma unroll
    for (int j = 0; j < 8; ++j) tmp.s[j] = tile[(lp + j) * 72 + d];
    *(uint4*)&vT[(size_t)(bh * 64 + d) * 512 + lc + lp] = *(uint4*)&tmp;
    __syncthreads();
  }
}

// ---------------- fused attention ----------------
// block: (q-tile of 16) x h x b ; 256 threads = 4 waves
// LDS: S fp32 16 rows x stride 516 (33 KB).  After softmax, P (bf16, 16x512,
// row stride 512 shorts, 16B-group XOR swizzle g^=row&7) overlays the same
// buffer; a __syncthreads separates last S read from first P write.
__global__ __launch_bounds__(256) void attn_kernel(const u16* __restrict__ qkv, const u16* __restrict__ vT,
                                                   const float* __restrict__ bias_table,
                                                   float* __restrict__ out) {
  __shared__ float s_lds[16 * 516];
  __shared__ float bias_lds[528];
  u16* p_lds = (u16*)s_lds;

  const int b = blockIdx.z, h = blockIdx.y, q0 = blockIdx.x * 16;
  const int t = threadIdx.x, l = t & 63, w = t >> 6;
  const int lr = l & 15, lq = l >> 4;
  // fold softmax scale and log2(e) so we can use exp2 (native v_exp_f32)
  const float scale2 = 0.044194173824159216f * 1.4426950408889634f;

  // preload bias slice: idx i corresponds to rel = (496 - q0) + i, i.e.
  // bias for (row r, col c) is bias_lds[c + 15 - r]
  {
    const int rel0 = 496 - q0;   // note: bias index never negative (q0<=496)
    for (int i = t; i < 527; i += 256)
      bias_lds[i] = bias_table[(size_t)(rel0 + i) * HH + h];
  }

  // ---- phase 1: S' = Q K^T * scale2 ; wave w owns key-cols [w*128, +128) ----
  bf16x8 aq0, aq1;
  {
    const u16* qrow = qkv + (size_t)(b * 512 + q0 + lr) * NQKV + h * 64;
    aq0 = *(const bf16x8*)(qrow + lq * 8);
    aq1 = *(const bf16x8*)(qrow + 32 + lq * 8);
  }
#pragma unroll
  for (int ct = 0; ct < 8; ++ct) {
    const int kcol = w * 128 + ct * 16;
    const u16* krow = qkv + (size_t)(b * 512 + kcol + lr) * NQKV + 512 + h * 64;
    bf16x8 bk0 = *(const bf16x8*)(krow + lq * 8);
    bf16x8 bk1 = *(const bf16x8*)(krow + 32 + lq * 8);
    f32x4 acc = {0.f, 0.f, 0.f, 0.f};
    acc = __builtin_amdgcn_mfma_f32_16x16x32_bf16(aq0, bk0, acc, 0, 0, 0);
    acc = __builtin_amdgcn_mfma_f32_16x16x32_bf16(aq1, bk1, acc, 0, 0, 0);
#pragma unroll
    for (int i = 0; i < 4; ++i)
      s_lds[(lq * 4 + i) * 516 + kcol + lr] = acc[i] * scale2;
  }
  __syncthreads();

  // ---- phase 2: softmax (exp2 domain) + post-softmax bias, P -> bf16 LDS ----
  {
    const int r = t >> 4, sub = t & 15;
    const float* srow = s_lds + r * 516;
    float v[32];
    float m = -1e30f;
#pragma unroll
    for (int j = 0; j < 4; ++j) {
      float4 u0 = *(const float4*)(srow + sub * 8 + j * 128);
      float4 u1 = *(const float4*)(srow + sub * 8 + j * 128 + 4);
      v[j*8+0]=u0.x; v[j*8+1]=u0.y; v[j*8+2]=u0.z; v[j*8+3]=u0.w;
      v[j*8+4]=u1.x; v[j*8+5]=u1.y; v[j*8+6]=u1.z; v[j*8+7]=u1.w;
    }
#pragma unroll
    for (int j = 0; j < 32; ++j) m = fmaxf(m, v[j]);
#pragma unroll
    for (int d = 1; d < 16; d <<= 1) m = fmaxf(m, __shfl_xor(m, d, 64));
    float s = 0.f;
#pragma unroll
    for (int j = 0; j < 32; ++j) { v[j] = exp2f(v[j] - m); s += v[j]; }
#pragma unroll
    for (int d = 1; d < 16; d <<= 1) s += __shfl_xor(s, d, 64);
    const float rinv = 1.0f / s;
    // bias add + bf16 pack (into registers; LDS still holds S for other rows)
    u16 pk[32];
#pragma unroll
    for (int j = 0; j < 4; ++j)
#pragma unroll
      for (int e = 0; e < 8; ++e) {
        int col = sub * 8 + j * 128 + e;
        float p = v[j * 8 + e] * rinv + bias_lds[col + 15 - r];
        pk[j * 8 + e] = f2b(p);
      }
    __syncthreads();   // all S reads done -> safe to overlay P
    u16* prow = p_lds + r * 512;
#pragma unroll
    for (int j = 0; j < 4; ++j) {
      int g = (sub + 16 * j) ^ (r & 7);
      *(uint4*)&prow[g * 8] = *(uint4*)&pk[j * 8];
    }
  }
  __syncthreads();

  // ---- phase 3: out = P @ V ; wave w owns d-tile [w*16, +16) ----
  f32x4 acc = {0.f, 0.f, 0.f, 0.f};
  const u16* vrow = vT + (size_t)((b * 8 + h) * 64 + w * 16 + lr) * 512;
  const u16* prow = p_lds + lr * 512;
#pragma unroll
  for (int kt = 0; kt < 16; ++kt) {
    int g = (4 * kt + lq) ^ (lr & 7);
    bf16x8 ap = *(const bf16x8*)&prow[g * 8];
    bf16x8 bv = *(const bf16x8*)(vrow + kt * 32 + lq * 8);
    acc = __builtin_amdgcn_mfma_f32_16x16x32_bf16(ap, bv, acc, 0, 0, 0);
  }
#pragma unroll
  for (int i = 0; i < 4; ++i) {
    int qg = q0 + lq * 4 + i;
    out[(size_t)(b * 512 + qg) * 512 + h * 64 + w * 16 + lr] = acc[i];
  }
}

// ---------------- LayerNorm (in-place on d_out) ----------------
__global__ __launch_bounds__(256) void ln_kernel(float* __restrict__ out,
                                                 const float* __restrict__ gamma,
                                                 const float* __restrict__ beta) {
  const int row = blockIdx.x;
  float* p = out + (size_t)row * 512;
  const int t = threadIdx.x;
  float a = p[t], b2 = p[t + 256];
  float s = a + b2, s2 = a * a + b2 * b2;
#pragma unroll
  for (int d = 1; d < 64; d <<= 1) { s += __shfl_xor(s, d, 64); s2 += __shfl_xor(s2, d, 64); }
  __shared__ float ps[4], ps2[4];
  if ((t & 63) == 0) { ps[t >> 6] = s; ps2[t >> 6] = s2; }
  __syncthreads();
  s = ps[0] + ps[1] + ps[2] + ps[3];
  s2 = ps2[0] + ps2[1] + ps2[2] + ps2[3];
  float mu = s * (1.0f / 512.0f);
  float var = s2 * (1.0f / 512.0f) - mu * mu;
  float rs = rsqrtf(var + 1e-5f);
  p[t]       = gamma[t]       * (a  - mu) * rs + beta[t];
  p[t + 256] = gamma[t + 256] * (b2 - mu) * rs + beta[t + 256];
}

extern "C" void kernel_launch(void* const* d_in, const int* in_sizes, int n_in,
                              void* d_out, int out_size, void* d_ws, size_t ws_size,
                              hipStream_t stream) {
  const float* x    = (const float*)d_in[0];
  const float* wq   = (const float*)d_in[1];
  const float* wk   = (const float*)d_in[2];
  const float* wv   = (const float*)d_in[3];
  const float* bias = (const float*)d_in[4];
  const float* gamma = (const float*)d_in[5];
  const float* beta  = (const float*)d_in[6];
  float* out = (float*)d_out;

  char* ws = (char*)d_ws;
  u16* xb   = (u16*)ws;                       // x in bf16 (reused as vT afterwards)
  u16* wcat = (u16*)(ws + XB_BYTES);          // concat weights bf16
  u16* qkv  = (u16*)(ws + QKV_OFF);           // MROWS x 1536 bf16
  u16* vT   = xb;                             // reuse: gemm is done with xb before transpose

  cvt_x<<<dim3((MROWS * CC) / 4 / 256), 256, 0, stream>>>(x, xb);
  cvt_w<<<dim3((NQKV * CC) / 4 / 256), 256, 0, stream>>>(wq, wk, wv, wcat);
  gemm_qkv<<<dim3(NQKV / 128, MROWS / 128), 256, 0, stream>>>(xb, wcat, qkv);
  transpose_v<<<dim3(256, 4), 256, 0, stream>>>(qkv, vT);
  attn_kernel<<<dim3(32, 8, 32), 256, 0, stream>>>(qkv, vT, bias, out);
  ln_kernel<<<dim3(MROWS), 256, 0, stream>>>(out, gamma, beta);
}

// Round 3
// 239.477 us; speedup vs baseline: 1.6633x; 1.2136x over previous
//
#include <hip/hip_runtime.h>

typedef unsigned short u16;
typedef __attribute__((ext_vector_type(8))) __bf16 bf16x8;
typedef __attribute__((ext_vector_type(4))) float f32x4;

// Problem dims
#define BB 32
#define LL 512
#define CC 512
#define HH 8
#define DH 64
#define MROWS (BB * LL)        // 16384
#define NQKV  (3 * CC)         // 1536

// workspace layout (bytes)
#define XB_BYTES ((size_t)MROWS * CC * 2)        // 16,777,216  (x bf16; later reused as vT)
#define WC_BYTES ((size_t)NQKV * CC * 2)         //  1,572,864  (wq|wk|wv bf16)
#define QKV_OFF  (XB_BYTES + WC_BYTES)           // qkv bf16: MROWS x 1536

__device__ inline u16 f2b(float f) {
  union { float f; unsigned u; } a; a.f = f;
  unsigned u = a.u;
  return (u16)((u + 0x7FFFu + ((u >> 16) & 1u)) >> 16);   // RNE, inputs are finite
}

// ---------------- conversion kernels ----------------
__global__ __launch_bounds__(256) void cvt_x(const float* __restrict__ x, u16* __restrict__ xb) {
  int i = blockIdx.x * 256 + threadIdx.x;       // one float4 per thread
  float4 v = ((const float4*)x)[i];
  ushort4 o;
  o.x = f2b(v.x); o.y = f2b(v.y); o.z = f2b(v.z); o.w = f2b(v.w);
  ((ushort4*)xb)[i] = o;
}

__global__ __launch_bounds__(256) void cvt_w(const float* __restrict__ wq, const float* __restrict__ wk,
                                             const float* __restrict__ wv, u16* __restrict__ wcat) {
  int i = blockIdx.x * 256 + threadIdx.x;       // one float4 per thread
  int e = i * 4;
  int n = e >> 9;                                // output row 0..1535
  int k = e & 511;
  const float* src = (n < 512) ? (wq + (size_t)n * 512)
                   : (n < 1024) ? (wk + (size_t)(n - 512) * 512)
                                : (wv + (size_t)(n - 1024) * 512);
  float4 v = *(const float4*)(src + k);
  ushort4 o;
  o.x = f2b(v.x); o.y = f2b(v.y); o.z = f2b(v.z); o.w = f2b(v.w);
  *(ushort4*)(wcat + (size_t)n * 512 + k) = o;
}

// ---------------- async global->LDS ----------------
typedef __attribute__((address_space(1))) void* as1_void_p;
typedef __attribute__((address_space(3))) void* as3_void_p;

__device__ inline void async16(const u16* g, u16* l) {
#if __has_builtin(__builtin_amdgcn_global_load_lds)
  __builtin_amdgcn_global_load_lds((as1_void_p)g, (as3_void_p)l, 16, 0, 0);
#else
  *(uint4*)l = *(const uint4*)g;
#endif
}

// ---------------- QKV projection GEMM ----------------
// A: xb (MROWS x 512 bf16, row-major), Bw: wcat (1536 x 512 bf16, row-major; y = x @ W^T)
// C: qkv (MROWS x 1536 bf16)
__global__ __launch_bounds__(256) void gemm_qkv(const u16* __restrict__ A, const u16* __restrict__ Bw,
                                                u16* __restrict__ Cm) {
  __shared__ u16 a_lds[128 * 32];
  __shared__ u16 b_lds[128 * 32];
  const int n0 = blockIdx.x * 128, m0 = blockIdx.y * 128;
  const int t = threadIdx.x, l = t & 63;
  const int wrow = ((t >> 7) & 1) * 64, wcol = ((t >> 6) & 1) * 64;
  const int lr = l & 15, lq = l >> 4;

  f32x4 acc[4][4] = {};

  for (int k0 = 0; k0 < 512; k0 += 32) {
    {
      int c0 = t, c1 = t + 256;
      async16(A  + (size_t)(m0 + (c0 >> 2)) * 512 + k0 + (c0 & 3) * 8, &a_lds[c0 * 8]);
      async16(A  + (size_t)(m0 + (c1 >> 2)) * 512 + k0 + (c1 & 3) * 8, &a_lds[c1 * 8]);
      async16(Bw + (size_t)(n0 + (c0 >> 2)) * 512 + k0 + (c0 & 3) * 8, &b_lds[c0 * 8]);
      async16(Bw + (size_t)(n0 + (c1 >> 2)) * 512 + k0 + (c1 & 3) * 8, &b_lds[c1 * 8]);
    }
    __syncthreads();
    bf16x8 af[4], bfr[4];
#pragma unroll
    for (int r = 0; r < 4; ++r) af[r]  = *(const bf16x8*)&a_lds[(wrow + r * 16 + lr) * 32 + lq * 8];
#pragma unroll
    for (int c = 0; c < 4; ++c) bfr[c] = *(const bf16x8*)&b_lds[(wcol + c * 16 + lr) * 32 + lq * 8];
#pragma unroll
    for (int r = 0; r < 4; ++r)
#pragma unroll
      for (int c = 0; c < 4; ++c)
        acc[r][c] = __builtin_amdgcn_mfma_f32_16x16x32_bf16(af[r], bfr[c], acc[r][c], 0, 0, 0);
    __syncthreads();
  }
  // epilogue: C/D layout col=lane&15, row=(lane>>4)*4+reg
#pragma unroll
  for (int r = 0; r < 4; ++r) {
#pragma unroll
    for (int i = 0; i < 4; ++i) {
      int m = m0 + wrow + r * 16 + lq * 4 + i;
      u16* crow = Cm + (size_t)m * NQKV + n0 + wcol;
#pragma unroll
      for (int c = 0; c < 4; ++c)
        crow[c * 16 + lr] = f2b(acc[r][c][i]);
    }
  }
}

// ---------------- V transpose: qkv V-part (b,l,h,d) -> vT[(b*8+h)*64+d][l] ----------------
__global__ __launch_bounds__(256) void transpose_v(const u16* __restrict__ qkv, u16* __restrict__ vT) {
  const int bh = blockIdx.x;                 // 0..255
  const int b = bh >> 3, h = bh & 7;
  const int lc0 = blockIdx.y * 128;
  __shared__ u16 tile[32 * 72];              // pad row stride 72 (16B aligned)
  const int t = threadIdx.x;
  for (int lc = lc0; lc < lc0 + 128; lc += 32) {
    int lrow = t >> 3, dcol = (t & 7) * 8;
    const u16* src = qkv + (size_t)(b * 512 + lc + lrow) * NQKV + 1024 + h * 64 + dcol;
    *(uint4*)&tile[lrow * 72 + dcol] = *(const uint4*)src;
    __syncthreads();
    int d = t >> 2, lp = (t & 3) * 8;
    union { ushort4 v4[2]; u16 s[8]; } tmp;
#pragma unroll
    for (int j = 0; j < 8; ++j) tmp.s[j] = tile[(lp + j) * 72 + d];
    *(uint4*)&vT[(size_t)(bh * 64 + d) * 512 + lc + lp] = *(uint4*)&tmp;
    __syncthreads();
  }
}

// ---------------- fused attention (S-transposed formulation) ----------------
// block: 32 queries x h x b ; 256 threads = 4 waves; wave w owns keys [w*128,+128)
// Phase 1: S^T = K Q^T (A=K-frags, B=Q-frags) -> C-layout: lane(lq,lr) holds
//   query = qt*16 + lr (column), keys = w*128 + ct*16 + lq*4 + i (row).
// Softmax over keys = in-register reduce (32 vals) + shfl over lq + tiny LDS
// cross-wave combine. S never goes to LDS; only bf16 P does.
// P LDS layout: P[q][key] row stride 512 u16, 16-u16 groups XOR-swizzled:
//   group' = (g & ~7) | ((g&7) ^ (q&7)).  b64 stores and b128 A-frag reads are
//   both minimum-phase (conflict-free in throughput terms).
__global__ __launch_bounds__(256) void attn_kernel(const u16* __restrict__ qkv, const u16* __restrict__ vT,
                                                   const float* __restrict__ bias_table,
                                                   float* __restrict__ out) {
  __shared__ u16 p_lds[32 * 512];            // 32 KB
  __shared__ float bias_lds[544];
  __shared__ float redm[4][32];
  __shared__ float reds[4][32];

  const int b = blockIdx.z, h = blockIdx.y, q0 = blockIdx.x * 32;
  const int t = threadIdx.x, l = t & 63, w = t >> 6;
  const int lr = l & 15, lq = l >> 4;
  const float scale2 = 0.044194173824159216f * 1.4426950408889634f; // scale*log2(e)

  // bias slice: bias for (q,key) = bias_lds[key + 31 - (q - q0)]
  {
    const int rel0 = 480 - q0;
    for (int i = t; i < 543; i += 256)
      bias_lds[i] = bias_table[(size_t)(rel0 + i) * HH + h];
  }

  // Q B-frags (2 query tiles of 16)
  bf16x8 bq[2][2];
#pragma unroll
  for (int qt = 0; qt < 2; ++qt) {
    const u16* qrow = qkv + (size_t)(b * 512 + q0 + qt * 16 + lr) * NQKV + h * 64;
    bq[qt][0] = *(const bf16x8*)(qrow + lq * 8);
    bq[qt][1] = *(const bf16x8*)(qrow + 32 + lq * 8);
  }

  // ---- phase 1: S^T tiles ----
  f32x4 sT[2][8];
#pragma unroll
  for (int ct = 0; ct < 8; ++ct) {
    const int kcol = w * 128 + ct * 16;
    const u16* krow = qkv + (size_t)(b * 512 + kcol + lr) * NQKV + 512 + h * 64;
    bf16x8 ak0 = *(const bf16x8*)(krow + lq * 8);
    bf16x8 ak1 = *(const bf16x8*)(krow + 32 + lq * 8);
#pragma unroll
    for (int qt = 0; qt < 2; ++qt) {
      f32x4 acc = {0.f, 0.f, 0.f, 0.f};
      acc = __builtin_amdgcn_mfma_f32_16x16x32_bf16(ak0, bq[qt][0], acc, 0, 0, 0);
      acc = __builtin_amdgcn_mfma_f32_16x16x32_bf16(ak1, bq[qt][1], acc, 0, 0, 0);
      sT[qt][ct] = acc;
    }
  }

  // ---- softmax: per-query max (in-register + shfl + cross-wave LDS) ----
  float mloc[2];
#pragma unroll
  for (int qt = 0; qt < 2; ++qt) {
    float m = sT[qt][0][0];
#pragma unroll
    for (int ct = 0; ct < 8; ++ct)
#pragma unroll
      for (int i = 0; i < 4; ++i) m = fmaxf(m, sT[qt][ct][i]);
    m = fmaxf(m, __shfl_xor(m, 16, 64));
    m = fmaxf(m, __shfl_xor(m, 32, 64));
    mloc[qt] = m;
  }
  if (lq == 0) { redm[w][lr] = mloc[0]; redm[w][16 + lr] = mloc[1]; }
  __syncthreads();
  float mfull[2];
#pragma unroll
  for (int qt = 0; qt < 2; ++qt)
    mfull[qt] = fmaxf(fmaxf(redm[0][qt * 16 + lr], redm[1][qt * 16 + lr]),
                      fmaxf(redm[2][qt * 16 + lr], redm[3][qt * 16 + lr]));

  // exp2 + per-query sum
  float sloc[2];
#pragma unroll
  for (int qt = 0; qt < 2; ++qt) {
    float s = 0.f;
#pragma unroll
    for (int ct = 0; ct < 8; ++ct)
#pragma unroll
      for (int i = 0; i < 4; ++i) {
        float e = exp2f((sT[qt][ct][i] - mfull[qt]) * scale2);
        sT[qt][ct][i] = e;
        s += e;
      }
    s += __shfl_xor(s, 16, 64);
    s += __shfl_xor(s, 32, 64);
    sloc[qt] = s;
  }
  if (lq == 0) { reds[w][lr] = sloc[0]; reds[w][16 + lr] = sloc[1]; }
  __syncthreads();
  float rinv[2];
#pragma unroll
  for (int qt = 0; qt < 2; ++qt)
    rinv[qt] = 1.0f / (reds[0][qt * 16 + lr] + reds[1][qt * 16 + lr] +
                       reds[2][qt * 16 + lr] + reds[3][qt * 16 + lr]);

  // ---- P = softmax + bias -> bf16 LDS (swizzled b64 stores) ----
#pragma unroll
  for (int qt = 0; qt < 2; ++qt) {
    const int qlocal = qt * 16 + lr;
    u16* prow = p_lds + qlocal * 512;
#pragma unroll
    for (int ct = 0; ct < 8; ++ct) {
      const int gsw = w * 8 + (ct ^ (lr & 7));
      u16 pk[4];
#pragma unroll
      for (int i = 0; i < 4; ++i) {
        int key = w * 128 + ct * 16 + lq * 4 + i;
        float p = sT[qt][ct][i] * rinv[qt] + bias_lds[key + 31 - qlocal];
        pk[i] = f2b(p);
      }
      *(uint2*)&prow[gsw * 16 + lq * 4] = *(uint2*)pk;
    }
  }
  __syncthreads();

  // ---- phase 3: out = P @ V ; wave w owns d-tile [w*16,+16) ----
  f32x4 acc[2] = {};
  const u16* vrow = vT + (size_t)((b * 8 + h) * 64 + w * 16 + lr) * 512;
  const u16* prow0 = p_lds + lr * 512;
  const u16* prow1 = p_lds + (16 + lr) * 512;
#pragma unroll
  for (int kt = 0; kt < 16; ++kt) {
    int g = 2 * kt + (lq >> 1);
    int gsw = (g & ~7) | ((g & 7) ^ (lr & 7));
    int off = gsw * 16 + (lq & 1) * 8;
    bf16x8 bv = *(const bf16x8*)(vrow + kt * 32 + lq * 8);
    bf16x8 ap0 = *(const bf16x8*)(prow0 + off);
    acc[0] = __builtin_amdgcn_mfma_f32_16x16x32_bf16(ap0, bv, acc[0], 0, 0, 0);
    bf16x8 ap1 = *(const bf16x8*)(prow1 + off);
    acc[1] = __builtin_amdgcn_mfma_f32_16x16x32_bf16(ap1, bv, acc[1], 0, 0, 0);
  }
#pragma unroll
  for (int qt = 0; qt < 2; ++qt)
#pragma unroll
    for (int i = 0; i < 4; ++i) {
      int qg = q0 + qt * 16 + lq * 4 + i;
      out[(size_t)(b * 512 + qg) * 512 + h * 64 + w * 16 + lr] = acc[qt][i];
    }
}

// ---------------- LayerNorm (in-place on d_out) ----------------
__global__ __launch_bounds__(256) void ln_kernel(float* __restrict__ out,
                                                 const float* __restrict__ gamma,
                                                 const float* __restrict__ beta) {
  const int row = blockIdx.x;
  float* p = out + (size_t)row * 512;
  const int t = threadIdx.x;
  float a = p[t], b2 = p[t + 256];
  float s = a + b2, s2 = a * a + b2 * b2;
#pragma unroll
  for (int d = 1; d < 64; d <<= 1) { s += __shfl_xor(s, d, 64); s2 += __shfl_xor(s2, d, 64); }
  __shared__ float ps[4], ps2[4];
  if ((t & 63) == 0) { ps[t >> 6] = s; ps2[t >> 6] = s2; }
  __syncthreads();
  s = ps[0] + ps[1] + ps[2] + ps[3];
  s2 = ps2[0] + ps2[1] + ps2[2] + ps2[3];
  float mu = s * (1.0f / 512.0f);
  float var = s2 * (1.0f / 512.0f) - mu * mu;
  float rs = rsqrtf(var + 1e-5f);
  p[t]       = gamma[t]       * (a  - mu) * rs + beta[t];
  p[t + 256] = gamma[t + 256] * (b2 - mu) * rs + beta[t + 256];
}

extern "C" void kernel_launch(void* const* d_in, const int* in_sizes, int n_in,
                              void* d_out, int out_size, void* d_ws, size_t ws_size,
                              hipStream_t stream) {
  const float* x    = (const float*)d_in[0];
  const float* wq   = (const float*)d_in[1];
  const float* wk   = (const float*)d_in[2];
  const float* wv   = (const float*)d_in[3];
  const float* bias = (const float*)d_in[4];
  const float* gamma = (const float*)d_in[5];
  const float* beta  = (const float*)d_in[6];
  float* out = (float*)d_out;

  char* ws = (char*)d_ws;
  u16* xb   = (u16*)ws;                       // x in bf16 (reused as vT afterwards)
  u16* wcat = (u16*)(ws + XB_BYTES);          // concat weights bf16
  u16* qkv  = (u16*)(ws + QKV_OFF);           // MROWS x 1536 bf16
  u16* vT   = xb;                             // reuse: gemm is done with xb before transpose

  cvt_x<<<dim3((MROWS * CC) / 4 / 256), 256, 0, stream>>>(x, xb);
  cvt_w<<<dim3((NQKV * CC) / 4 / 256), 256, 0, stream>>>(wq, wk, wv, wcat);
  gemm_qkv<<<dim3(NQKV / 128, MROWS / 128), 256, 0, stream>>>(xb, wcat, qkv);
  transpose_v<<<dim3(256, 4), 256, 0, stream>>>(qkv, vT);
  attn_kernel<<<dim3(LL / 32, HH, BB), 256, 0, stream>>>(qkv, vT, bias, out);
  ln_kernel<<<dim3(MROWS), 256, 0, stream>>>(out, gamma, beta);
}